// Round 1
// baseline (26.320 us; speedup 1.0000x reference)
//
#include <hip/hip_runtime.h>
#include <math.h>

#define NF 64  // IN_FEATS

// ---------------------------------------------------------------------------
// Kernel 0: detect index dtype. If the src buffer is int64 (values < 2^31),
// every odd int32 word is zero. If int32, odd words are random node indices.
// Reads only the first 512 bytes — safe under both interpretations.
// ---------------------------------------------------------------------------
__global__ void detect_idx64_kernel(const void* __restrict__ idx, int* __restrict__ flag) {
    int l = threadIdx.x;  // 0..63, one wave
    const int* p = (const int*)idx;
    int v = p[2 * l + 1];
    unsigned long long b = __ballot(v == 0);
    if (l == 0) *flag = (b == ~0ull) ? 1 : 0;
}

// ---------------------------------------------------------------------------
// Kernel 1: per-node scores  s_u[n] = h[n]·W[:64],  s_v[n] = h[n]·W[64:]
// One wave per node; lane l owns feature l. Coalesced h reads; butterfly
// shuffle reduction over 64 lanes for both dot products simultaneously.
// ---------------------------------------------------------------------------
__global__ void node_scores_kernel(const float* __restrict__ h,
                                   const float* __restrict__ W,
                                   float2* __restrict__ S, int nNodes) {
    int gtid = blockIdx.x * blockDim.x + threadIdx.x;
    int node = gtid >> 6;
    int lane = gtid & 63;
    if (node >= nNodes) return;

    float x  = h[node * NF + lane];
    float su = x * W[lane];
    float sv = x * W[NF + lane];

    #pragma unroll
    for (int off = 32; off > 0; off >>= 1) {
        su += __shfl_xor(su, off, 64);
        sv += __shfl_xor(sv, off, 64);
    }
    if (lane == 0) S[node] = make_float2(su, sv);
}

// ---------------------------------------------------------------------------
// Kernel 2: per-edge  out[e] = sigmoid(s_u[src[e]] + s_v[dst[e]] + b)
// Score table (400 KB) is L2-resident; src/dst/out streamed coalesced.
// ---------------------------------------------------------------------------
__global__ void edge_kernel(const void* __restrict__ srcv,
                            const void* __restrict__ dstv,
                            const float2* __restrict__ S,
                            const float* __restrict__ b,
                            const int* __restrict__ flag,
                            float* __restrict__ out, int nE) {
    int e = blockIdx.x * blockDim.x + threadIdx.x;
    if (e >= nE) return;

    long long s, d;
    if (*flag) {  // wave-uniform branch
        s = ((const long long*)srcv)[e];
        d = ((const long long*)dstv)[e];
    } else {
        s = (long long)((const int*)srcv)[e];
        d = (long long)((const int*)dstv)[e];
    }
    float logit = S[s].x + S[d].y + b[0];
    out[e] = 1.0f / (1.0f + __expf(-logit));
}

extern "C" void kernel_launch(void* const* d_in, const int* in_sizes, int n_in,
                              void* d_out, int out_size, void* d_ws, size_t ws_size,
                              hipStream_t stream) {
    const float* h   = (const float*)d_in[0];
    const void*  src = d_in[1];
    const void*  dst = d_in[2];
    const float* W   = (const float*)d_in[3];
    const float* b   = (const float*)d_in[4];
    float* out = (float*)d_out;

    int nNodes = in_sizes[0] / NF;   // 50000
    int nE     = in_sizes[1];        // 800000

    int*    flag = (int*)d_ws;
    float2* S    = (float2*)((char*)d_ws + 256);  // 50000*8 B = 400 KB scratch

    detect_idx64_kernel<<<1, 64, 0, stream>>>(src, flag);

    int nodeBlocks = (nNodes + 3) / 4;  // 4 waves (nodes) per 256-thread block
    node_scores_kernel<<<nodeBlocks, 256, 0, stream>>>(h, W, S, nNodes);

    int edgeBlocks = (nE + 255) / 256;
    edge_kernel<<<edgeBlocks, 256, 0, stream>>>(src, dst, S, b, flag, out, nE);
}

// Round 2
// 19.152 us; speedup vs baseline: 1.3743x; 1.3743x over previous
//
#include <hip/hip_runtime.h>
#include <math.h>

#define NF 64  // IN_FEATS

// ---------------------------------------------------------------------------
// Kernel 1: per-node scores  s_u[n] = h[n]·W[:64],  s_v[n] = h[n]·W[64:]
// 4 nodes per wave: lane = 16*group + fl; lane loads float4 of features
// fl*4..fl*4+3 of its group's node (16 B/lane, fully coalesced), segmented
// 16-lane butterfly reduction. Wave 0 of block 0 also detects the index
// dtype (int64 → every odd int32 word of src is 0) and writes `flag`.
// ---------------------------------------------------------------------------
__global__ void node_scores_kernel(const float4* __restrict__ h4,
                                   const float4* __restrict__ W4,
                                   float2* __restrict__ S, int nNodes,
                                   const void* __restrict__ src,
                                   int* __restrict__ flag) {
    if (blockIdx.x == 0 && threadIdx.x < 64) {
        const int* p = (const int*)src;
        int v = p[2 * threadIdx.x + 1];
        unsigned long long bal = __ballot(v == 0);
        if (threadIdx.x == 0) *flag = (bal == ~0ull) ? 1 : 0;
    }

    int gtid  = blockIdx.x * blockDim.x + threadIdx.x;
    int wave  = gtid >> 6;
    int lane  = gtid & 63;
    int group = lane >> 4;   // which of the wave's 4 nodes
    int fl    = lane & 15;   // feature block (4 floats)
    int node  = wave * 4 + group;
    if (node >= nNodes) return;

    float4 x  = h4[node * 16 + fl];
    float4 wu = W4[fl];
    float4 wv = W4[16 + fl];
    float su = x.x * wu.x + x.y * wu.y + x.z * wu.z + x.w * wu.w;
    float sv = x.x * wv.x + x.y * wv.y + x.z * wv.z + x.w * wv.w;

    #pragma unroll
    for (int off = 1; off < 16; off <<= 1) {  // stays within 16-lane segment
        su += __shfl_xor(su, off, 64);
        sv += __shfl_xor(sv, off, 64);
    }
    if (fl == 0) S[node] = make_float2(su, sv);
}

// ---------------------------------------------------------------------------
// Kernel 2: out[e] = sigmoid(s_u[src[e]] + s_v[dst[e]] + b), 4 edges/thread.
// Index loads as int4 (int64 data: low dword of each 8-byte pair is the
// index, so one int4 covers 2 edges; int32 data: one int4 covers 4 edges).
// 8 independent S-gathers per thread hide L2 latency; float4 output store.
// ---------------------------------------------------------------------------
__global__ void edge_kernel(const void* __restrict__ srcv,
                            const void* __restrict__ dstv,
                            const float2* __restrict__ S,
                            const float* __restrict__ b,
                            const int* __restrict__ flag,
                            float4* __restrict__ out4, int nE4) {
    int t = blockIdx.x * blockDim.x + threadIdx.x;
    if (t >= nE4) return;

    int s0, s1, s2, s3, d0, d1, d2, d3;
    if (*flag) {  // wave-uniform: indices are int64, take low dwords
        const int4* sp = (const int4*)srcv;
        const int4* dp = (const int4*)dstv;
        int4 a = sp[2 * t], c = sp[2 * t + 1];
        int4 e = dp[2 * t], f = dp[2 * t + 1];
        s0 = a.x; s1 = a.z; s2 = c.x; s3 = c.z;
        d0 = e.x; d1 = e.z; d2 = f.x; d3 = f.z;
    } else {      // int32
        int4 a = ((const int4*)srcv)[t];
        int4 e = ((const int4*)dstv)[t];
        s0 = a.x; s1 = a.y; s2 = a.z; s3 = a.w;
        d0 = e.x; d1 = e.y; d2 = e.z; d3 = e.w;
    }

    float2 su0 = S[s0], su1 = S[s1], su2 = S[s2], su3 = S[s3];
    float2 dv0 = S[d0], dv1 = S[d1], dv2 = S[d2], dv3 = S[d3];
    float bias = b[0];

    float l0 = su0.x + dv0.y + bias;
    float l1 = su1.x + dv1.y + bias;
    float l2 = su2.x + dv2.y + bias;
    float l3 = su3.x + dv3.y + bias;

    out4[t] = make_float4(1.0f / (1.0f + __expf(-l0)),
                          1.0f / (1.0f + __expf(-l1)),
                          1.0f / (1.0f + __expf(-l2)),
                          1.0f / (1.0f + __expf(-l3)));
}

extern "C" void kernel_launch(void* const* d_in, const int* in_sizes, int n_in,
                              void* d_out, int out_size, void* d_ws, size_t ws_size,
                              hipStream_t stream) {
    const float* h   = (const float*)d_in[0];
    const void*  src = d_in[1];
    const void*  dst = d_in[2];
    const float* W   = (const float*)d_in[3];
    const float* b   = (const float*)d_in[4];
    float* out = (float*)d_out;

    int nNodes = in_sizes[0] / NF;   // 50000
    int nE     = in_sizes[1];        // 800000

    int*    flag = (int*)d_ws;
    float2* S    = (float2*)((char*)d_ws + 256);  // 50000*8 B = 400 KB scratch

    // 16 nodes per 256-thread block (4 waves × 4 nodes)
    int nodeBlocks = (nNodes + 15) / 16;
    node_scores_kernel<<<nodeBlocks, 256, 0, stream>>>(
        (const float4*)h, (const float4*)W, S, nNodes, src, flag);

    int nE4 = nE / 4;                // 200000 (nE divisible by 4)
    int edgeBlocks = (nE4 + 255) / 256;
    edge_kernel<<<edgeBlocks, 256, 0, stream>>>(src, dst, S, b, flag,
                                                (float4*)out, nE4);
}